// Round 1
// 1189.674 us; speedup vs baseline: 1.2563x; 1.2563x over previous
//
#include <hip/hip_runtime.h>
#include <hip/hip_bf16.h>
#include <math.h>

// Problem constants
#define B 4
#define S 2048
#define D 512
#define H 8
#define HD 64
#define M_TOT (B * S)              // 8192 rows in the [B*S, D] view
#define X_SIZE (B * S * D)         // 4194304 elements
#define STRIDE_BH (S * HD)         // 131072  ([B,H,S,HD] h-stride)
#define STRIDE_B (H * S * HD)      // 1048576 ([B,H,S,HD] b-stride)

typedef __attribute__((ext_vector_type(8))) short bf16x8;
typedef __attribute__((ext_vector_type(4))) float f32x4;
typedef __attribute__((ext_vector_type(4))) unsigned short u16x4;

__device__ __forceinline__ unsigned short f2b(float f) {
  __hip_bfloat16 h = __float2bfloat16(f);   // RNE
  return *reinterpret_cast<unsigned short*>(&h);
}

// ---------------------------------------------------------------------------
// Projection GEMM (bf16 MFMA): acc[m,n] = sum_k X[m,k]*W[n,k] + bias[n].
// 128x64 tile, BK=64, 4 waves (2x2), fp32->bf16 cvt during LDS staging.
// TRANS==0: out[b,h,s,hd]  (q, k)
// TRANS==1: out[b,h,hd,s]  (vT) — MFMA operands swapped so the accumulator
//           is transposed and the epilogue writes contiguous s-runs.
// ---------------------------------------------------------------------------
template <int TRANS>
__global__ __launch_bounds__(256) void gemm_proj(
    const float* __restrict__ X, const float* __restrict__ W,
    const float* __restrict__ bias, __hip_bfloat16* __restrict__ out) {
  // stride 72 elems = 144 B: 16B-aligned for ds_read_b128, rows advance 4
  // banks -> worst 2-way aliasing (free).
  __shared__ __hip_bfloat16 As[128][72];
  __shared__ __hip_bfloat16 Bs[64][72];
  const int tid = threadIdx.x;
  const int lane = tid & 63;
  const int wave = tid >> 6;
  const int wr = wave >> 1, wc = wave & 1;   // wave grid 2x2 over 128x64
  const int l15 = lane & 15, quad = lane >> 4;
  const int h = blockIdx.x;                  // one head per 64-wide n-tile
  const int n0 = h * 64;
  const int m0 = blockIdx.y * 128;

  f32x4 acc[4][2] = {};

  for (int k0 = 0; k0 < D; k0 += 64) {
    // stage A: 128x64 fp32 -> bf16 (2048 float4s, 8/thread, coalesced rows)
#pragma unroll
    for (int i = 0; i < 8; ++i) {
      int idx = tid + i * 256;
      int r = idx >> 4, c4 = idx & 15;
      const float4 x = *(const float4*)&X[(size_t)(m0 + r) * D + k0 + c4 * 4];
      u16x4 pk;
      pk[0] = f2b(x.x); pk[1] = f2b(x.y); pk[2] = f2b(x.z); pk[3] = f2b(x.w);
      *(u16x4*)&As[r][c4 * 4] = pk;
    }
    // stage B: 64x64 fp32 -> bf16 (1024 float4s, 4/thread)
#pragma unroll
    for (int i = 0; i < 4; ++i) {
      int idx = tid + i * 256;
      int r = idx >> 4, c4 = idx & 15;
      const float4 w = *(const float4*)&W[(size_t)(n0 + r) * D + k0 + c4 * 4];
      u16x4 pk;
      pk[0] = f2b(w.x); pk[1] = f2b(w.y); pk[2] = f2b(w.z); pk[3] = f2b(w.w);
      *(u16x4*)&Bs[r][c4 * 4] = pk;
    }
    __syncthreads();

    bf16x8 a[4][2], b[2][2];
#pragma unroll
    for (int mf = 0; mf < 4; ++mf) {
      a[mf][0] = *(const bf16x8*)&As[wr * 64 + mf * 16 + l15][quad * 8];
      a[mf][1] = *(const bf16x8*)&As[wr * 64 + mf * 16 + l15][32 + quad * 8];
    }
#pragma unroll
    for (int nf = 0; nf < 2; ++nf) {
      b[nf][0] = *(const bf16x8*)&Bs[wc * 32 + nf * 16 + l15][quad * 8];
      b[nf][1] = *(const bf16x8*)&Bs[wc * 32 + nf * 16 + l15][32 + quad * 8];
    }
#pragma unroll
    for (int mf = 0; mf < 4; ++mf)
#pragma unroll
      for (int nf = 0; nf < 2; ++nf) {
        if (TRANS) {
          acc[mf][nf] = __builtin_amdgcn_mfma_f32_16x16x32_bf16(b[nf][0], a[mf][0], acc[mf][nf], 0, 0, 0);
          acc[mf][nf] = __builtin_amdgcn_mfma_f32_16x16x32_bf16(b[nf][1], a[mf][1], acc[mf][nf], 0, 0, 0);
        } else {
          acc[mf][nf] = __builtin_amdgcn_mfma_f32_16x16x32_bf16(a[mf][0], b[nf][0], acc[mf][nf], 0, 0, 0);
          acc[mf][nf] = __builtin_amdgcn_mfma_f32_16x16x32_bf16(a[mf][1], b[nf][1], acc[mf][nf], 0, 0, 0);
        }
      }
    __syncthreads();
  }

  if (!TRANS) {
    // D-layout: row(m) = quad*4+r, col(n) = l15
#pragma unroll
    for (int mf = 0; mf < 4; ++mf)
#pragma unroll
      for (int r = 0; r < 4; ++r) {
        int m = m0 + wr * 64 + mf * 16 + quad * 4 + r;
        int bb = m >> 11, s = m & 2047;
        __hip_bfloat16* obh = out + (size_t)bb * STRIDE_B + (size_t)h * STRIDE_BH;
#pragma unroll
        for (int nf = 0; nf < 2; ++nf) {
          int hd = wc * 32 + nf * 16 + l15;
          obh[(size_t)s * HD + hd] =
              __float2bfloat16(acc[mf][nf][r] + bias[n0 + hd]);
        }
      }
  } else {
    // operands swapped -> row = n (hd), col = m (s): contiguous-s writes
#pragma unroll
    for (int mf = 0; mf < 4; ++mf)
#pragma unroll
      for (int r = 0; r < 4; ++r)
#pragma unroll
        for (int nf = 0; nf < 2; ++nf) {
          int hd = wc * 32 + nf * 16 + quad * 4 + r;
          int m = m0 + wr * 64 + mf * 16 + l15;
          int bb = m >> 11, s = m & 2047;
          __hip_bfloat16* obh = out + (size_t)bb * STRIDE_B + (size_t)h * STRIDE_BH;
          obh[(size_t)hd * S + s] =
              __float2bfloat16(acc[mf][nf][r] + bias[n0 + hd]);
        }
  }
}

// ---------------------------------------------------------------------------
// Fused attention: unchanged two-pass structure; epilogue now writes O as
// bf16 directly into the flat [B,S,D] layout consumed by gemm_out.
// ---------------------------------------------------------------------------
__global__ __launch_bounds__(256) void attn_fused(
    const __hip_bfloat16* __restrict__ q, const __hip_bfloat16* __restrict__ k,
    const __hip_bfloat16* __restrict__ vT, const int* __restrict__ mask,
    float* __restrict__ dist, __hip_bfloat16* __restrict__ attn) {
  __shared__ __hip_bfloat16 ps[4][16][72];   // per-wave P strip

  const int tid = threadIdx.x;
  const int wave = tid >> 6;
  const int lane = tid & 63;
  const int l15 = lane & 15;
  const int quad = lane >> 4;
  const int qt = blockIdx.x >> 5;            // consecutive blocks share the mask
  const int bh = blockIdx.x & 31;            // strip (8 heads per batch) -> L2 reuse
  const int b = bh >> 3;
  const int row0 = qt * 64 + wave * 16;      // this wave's 16 query rows

  const __hip_bfloat16* qb  = q  + (size_t)bh * STRIDE_BH;
  const __hip_bfloat16* kb  = k  + (size_t)bh * STRIDE_BH;
  const __hip_bfloat16* vtb = vT + (size_t)bh * STRIDE_BH;   // [HD][S]
  const int* mb = mask + (size_t)b * S * S;
  float* distb = dist + (size_t)bh * S * S;
  // flat [b, s, d] with d = h*64 + hd
  __hip_bfloat16* af = attn + (size_t)b * S * D + (size_t)(bh & 7) * HD;

  const bf16x8 qf0 = *(const bf16x8*)(qb + (size_t)(row0 + l15) * HD + quad * 8);
  const bf16x8 qf1 = *(const bf16x8*)(qb + (size_t)(row0 + l15) * HD + 32 + quad * 8);

  float lpart[4] = {0.f, 0.f, 0.f, 0.f};

  // ---- pass A: row sums ----
  for (int kt = 0; kt < 32; ++kt) {
    const int col0 = kt * 64;
#pragma unroll
    for (int ct = 0; ct < 4; ++ct) {
      const int col = col0 + ct * 16 + l15;
      const bf16x8 kf0 = *(const bf16x8*)(kb + (size_t)col * HD + quad * 8);
      const bf16x8 kf1 = *(const bf16x8*)(kb + (size_t)col * HD + 32 + quad * 8);
      f32x4 s = {0.f, 0.f, 0.f, 0.f};
      s = __builtin_amdgcn_mfma_f32_16x16x32_bf16(qf0, kf0, s, 0, 0, 0);
      s = __builtin_amdgcn_mfma_f32_16x16x32_bf16(qf1, kf1, s, 0, 0, 0);
#pragma unroll
      for (int r = 0; r < 4; ++r) {
        int row = row0 + quad * 4 + r;
        int msk = mb[(size_t)row * S + col];
        float e = msk ? 0.f : __expf(s[r] * 0.125f);
        lpart[r] += e;
      }
    }
  }
#pragma unroll
  for (int r = 0; r < 4; ++r) {
    float v = lpart[r];
    v += __shfl_xor(v, 1, 64);
    v += __shfl_xor(v, 2, 64);
    v += __shfl_xor(v, 4, 64);
    v += __shfl_xor(v, 8, 64);
    lpart[r] = 1.0f / v;
  }

  // ---- pass B: dist write + O = P.V ----
  f32x4 oacc[4] = {{0.f, 0.f, 0.f, 0.f}, {0.f, 0.f, 0.f, 0.f},
                   {0.f, 0.f, 0.f, 0.f}, {0.f, 0.f, 0.f, 0.f}};
  for (int kt = 0; kt < 32; ++kt) {
    const int col0 = kt * 64;
#pragma unroll
    for (int ct = 0; ct < 4; ++ct) {
      const int col = col0 + ct * 16 + l15;
      const bf16x8 kf0 = *(const bf16x8*)(kb + (size_t)col * HD + quad * 8);
      const bf16x8 kf1 = *(const bf16x8*)(kb + (size_t)col * HD + 32 + quad * 8);
      f32x4 s = {0.f, 0.f, 0.f, 0.f};
      s = __builtin_amdgcn_mfma_f32_16x16x32_bf16(qf0, kf0, s, 0, 0, 0);
      s = __builtin_amdgcn_mfma_f32_16x16x32_bf16(qf1, kf1, s, 0, 0, 0);
#pragma unroll
      for (int r = 0; r < 4; ++r) {
        int row = row0 + quad * 4 + r;
        int msk = mb[(size_t)row * S + col];
        float e = msk ? 0.f : __expf(s[r] * 0.125f);
        float p = e * lpart[r];
        distb[(size_t)row * S + col] = p;
        ps[wave][quad * 4 + r][ct * 16 + l15] = __float2bfloat16(p);
      }
    }
    const bf16x8 pa0 = *(const bf16x8*)&ps[wave][l15][quad * 8];
    const bf16x8 pa1 = *(const bf16x8*)&ps[wave][l15][32 + quad * 8];
#pragma unroll
    for (int ct = 0; ct < 4; ++ct) {
      const __hip_bfloat16* vrow = vtb + (size_t)(ct * 16 + l15) * S + col0;
      const bf16x8 vf0 = *(const bf16x8*)(vrow + quad * 8);
      const bf16x8 vf1 = *(const bf16x8*)(vrow + 32 + quad * 8);
      oacc[ct] = __builtin_amdgcn_mfma_f32_16x16x32_bf16(pa0, vf0, oacc[ct], 0, 0, 0);
      oacc[ct] = __builtin_amdgcn_mfma_f32_16x16x32_bf16(pa1, vf1, oacc[ct], 0, 0, 0);
    }
  }

  // write O as bf16 into flat [B,S,D]
#pragma unroll
  for (int ct = 0; ct < 4; ++ct)
#pragma unroll
    for (int r = 0; r < 4; ++r) {
      int row = row0 + quad * 4 + r;
      af[(size_t)row * D + ct * 16 + l15] = __float2bfloat16(oacc[ct][r]);
    }
}

// ---------------------------------------------------------------------------
// Output GEMM (bf16 MFMA): x[m,n] = sum_k attn_flat[m,k]*Wo[n,k] + bo[n].
// A is bf16 row-major [8192,512] (written by attn_fused); Wo converted fp32->
// bf16 during staging; fp32 accumulate + fp32 output.
// ---------------------------------------------------------------------------
__global__ __launch_bounds__(256) void gemm_out(
    const __hip_bfloat16* __restrict__ Abf, const float* __restrict__ W,
    const float* __restrict__ bias, float* __restrict__ outp) {
  __shared__ __hip_bfloat16 As[128][72];
  __shared__ __hip_bfloat16 Bs[64][72];
  const int tid = threadIdx.x;
  const int lane = tid & 63;
  const int wave = tid >> 6;
  const int wr = wave >> 1, wc = wave & 1;
  const int l15 = lane & 15, quad = lane >> 4;
  const int n0 = blockIdx.x * 64;
  const int m0 = blockIdx.y * 128;

  f32x4 acc[4][2] = {};

  for (int k0 = 0; k0 < D; k0 += 64) {
    // stage A: 128x64 bf16, 16B chunks (1024 chunks, 4/thread)
#pragma unroll
    for (int i = 0; i < 4; ++i) {
      int idx = tid + i * 256;
      int r = idx >> 3, c8 = idx & 7;
      *(bf16x8*)&As[r][c8 * 8] =
          *(const bf16x8*)&Abf[(size_t)(m0 + r) * D + k0 + c8 * 8];
    }
    // stage B: 64x64 fp32 -> bf16
#pragma unroll
    for (int i = 0; i < 4; ++i) {
      int idx = tid + i * 256;
      int r = idx >> 4, c4 = idx & 15;
      const float4 w = *(const float4*)&W[(size_t)(n0 + r) * D + k0 + c4 * 4];
      u16x4 pk;
      pk[0] = f2b(w.x); pk[1] = f2b(w.y); pk[2] = f2b(w.z); pk[3] = f2b(w.w);
      *(u16x4*)&Bs[r][c4 * 4] = pk;
    }
    __syncthreads();

    bf16x8 a[4][2], b[2][2];
#pragma unroll
    for (int mf = 0; mf < 4; ++mf) {
      a[mf][0] = *(const bf16x8*)&As[wr * 64 + mf * 16 + l15][quad * 8];
      a[mf][1] = *(const bf16x8*)&As[wr * 64 + mf * 16 + l15][32 + quad * 8];
    }
#pragma unroll
    for (int nf = 0; nf < 2; ++nf) {
      b[nf][0] = *(const bf16x8*)&Bs[wc * 32 + nf * 16 + l15][quad * 8];
      b[nf][1] = *(const bf16x8*)&Bs[wc * 32 + nf * 16 + l15][32 + quad * 8];
    }
#pragma unroll
    for (int mf = 0; mf < 4; ++mf)
#pragma unroll
      for (int nf = 0; nf < 2; ++nf) {
        acc[mf][nf] = __builtin_amdgcn_mfma_f32_16x16x32_bf16(a[mf][0], b[nf][0], acc[mf][nf], 0, 0, 0);
        acc[mf][nf] = __builtin_amdgcn_mfma_f32_16x16x32_bf16(a[mf][1], b[nf][1], acc[mf][nf], 0, 0, 0);
      }
    __syncthreads();
  }

#pragma unroll
  for (int mf = 0; mf < 4; ++mf)
#pragma unroll
    for (int r = 0; r < 4; ++r) {
      int m = m0 + wr * 64 + mf * 16 + quad * 4 + r;
#pragma unroll
      for (int nf = 0; nf < 2; ++nf) {
        int n = n0 + wc * 32 + nf * 16 + l15;
        outp[(size_t)m * D + n] = acc[mf][nf][r] + bias[n];
      }
    }
}

// ---------------------------------------------------------------------------
extern "C" void kernel_launch(void* const* d_in, const int* in_sizes, int n_in,
                              void* d_out, int out_size, void* d_ws, size_t ws_size,
                              hipStream_t stream) {
  const float* Q    = (const float*)d_in[0];
  const float* K    = (const float*)d_in[1];
  const float* V    = (const float*)d_in[2];
  const int*   mask = (const int*)d_in[3];
  const float* Wq   = (const float*)d_in[4];
  const float* bq   = (const float*)d_in[5];
  const float* Wk   = (const float*)d_in[6];
  const float* bk   = (const float*)d_in[7];
  const float* Wv   = (const float*)d_in[8];
  const float* bv   = (const float*)d_in[9];
  const float* Wo   = (const float*)d_in[10];
  const float* bo   = (const float*)d_in[11];

  float* x_out = (float*)d_out;              // [B,S,D]
  float* dist  = x_out + (size_t)X_SIZE;     // [B,H,S,S]

  __hip_bfloat16* qb  = (__hip_bfloat16*)d_ws;     // [B,H,S,HD]  bf16
  __hip_bfloat16* kbf = qb + (size_t)X_SIZE;       // [B,H,S,HD]  bf16
  __hip_bfloat16* vtb = kbf + (size_t)X_SIZE;      // [B,H,HD,S]  bf16
  __hip_bfloat16* abf = vtb + (size_t)X_SIZE;      // [B,S,D]     bf16 (flat O)

  dim3 blk(256);
  dim3 g(D / 64, M_TOT / 128);               // (8, 64)

  gemm_proj<0><<<g, blk, 0, stream>>>(Q, Wq, bq, qb);
  gemm_proj<0><<<g, blk, 0, stream>>>(K, Wk, bk, kbf);
  gemm_proj<1><<<g, blk, 0, stream>>>(V, Wv, bv, vtb);
  attn_fused<<<dim3(B * H * S / 64), blk, 0, stream>>>(qb, kbf, vtb, mask, dist, abf);
  gemm_out<<<g, blk, 0, stream>>>(abf, Wo, bo, x_out);
}

// Round 2
// 1017.585 us; speedup vs baseline: 1.4687x; 1.1691x over previous
//
#include <hip/hip_runtime.h>
#include <hip/hip_bf16.h>
#include <math.h>

// Problem constants
#define B 4
#define S 2048
#define D 512
#define H 8
#define HD 64
#define M_TOT (B * S)              // 8192 rows in the [B*S, D] view
#define X_SIZE (B * S * D)         // 4194304 elements
#define STRIDE_BH (S * HD)         // 131072  ([B,H,S,HD] h-stride)
#define STRIDE_B (H * S * HD)      // 1048576 ([B,H,S,HD] b-stride)
#define SW64 (S / 64)              // 32 mask words per row

typedef __attribute__((ext_vector_type(8))) short bf16x8;
typedef __attribute__((ext_vector_type(4))) float f32x4;

// ---------------------------------------------------------------------------
// cvt_all: one pass converting Q,K,V (fp32 [B*S,D]) and Wq,Wk,Wv,Wo (fp32
// [D,D]) to bf16, laid out contiguously in the workspace:
//   Qb | Kb | Vb | Wqb | Wkb | Wvb | Wob
// ---------------------------------------------------------------------------
__global__ __launch_bounds__(256) void cvt_all(
    const float* __restrict__ Q, const float* __restrict__ K,
    const float* __restrict__ V, const float* __restrict__ Wq,
    const float* __restrict__ Wk, const float* __restrict__ Wv,
    const float* __restrict__ Wo, __hip_bfloat16* __restrict__ outb) {
  const int NX = X_SIZE / 8;           // 524288 chunks of 8 floats
  const int NW = (D * D) / 8;          // 32768
  const int total = 3 * NX + 4 * NW;   // 1703936
  int c = blockIdx.x * 256 + threadIdx.x;
  const int stride = gridDim.x * 256;
  for (; c < total; c += stride) {
    const float* src;
    int off;
    if (c < NX)          { src = Q;  off = c; }
    else if (c < 2 * NX) { src = K;  off = c - NX; }
    else if (c < 3 * NX) { src = V;  off = c - 2 * NX; }
    else {
      int wc = c - 3 * NX;
      int wi = wc >> 15;               // / NW
      src = (wi == 0) ? Wq : (wi == 1) ? Wk : (wi == 2) ? Wv : Wo;
      off = wc & (NW - 1);
    }
    const float4 x0 = *(const float4*)&src[(size_t)off * 8];
    const float4 x1 = *(const float4*)&src[(size_t)off * 8 + 4];
    bf16x8 pk;
    __hip_bfloat16* p = (__hip_bfloat16*)&pk;
    p[0] = __float2bfloat16(x0.x); p[1] = __float2bfloat16(x0.y);
    p[2] = __float2bfloat16(x0.z); p[3] = __float2bfloat16(x0.w);
    p[4] = __float2bfloat16(x1.x); p[5] = __float2bfloat16(x1.y);
    p[6] = __float2bfloat16(x1.z); p[7] = __float2bfloat16(x1.w);
    *(bf16x8*)&outb[(size_t)c * 8] = pk;
  }
}

// ---------------------------------------------------------------------------
// mask_pack: [B,S,S] int32 -> [B,S,S/64] u64 bitmask via wave ballot.
// bit c of word (row, w) == mask[row][w*64 + c] != 0.
// Shrinks 67 MB of mask traffic to a 2 MB L2-resident structure.
// ---------------------------------------------------------------------------
__global__ __launch_bounds__(256) void mask_pack(
    const int* __restrict__ mask, unsigned long long* __restrict__ mbits) {
  const int lane = threadIdx.x & 63;
  const int wid = threadIdx.x >> 6;
  const size_t nwords = (size_t)B * S * SW64;          // 262144
  size_t w = (size_t)blockIdx.x * 4 + wid;
  const size_t stride = (size_t)gridDim.x * 4;
  for (; w < nwords; w += stride) {
    int m = mask[w * 64 + lane];
    unsigned long long bits = __ballot(m != 0);
    if (lane == 0) mbits[w] = bits;
  }
}

// ---------------------------------------------------------------------------
// Projection GEMM (pure bf16 MFMA): acc[m,n] = sum_k X[m,k]*W[n,k] + bias[n].
// 64x64 tile, BK=64, 4 waves (2x2). Inputs pre-converted bf16 -> staging is
// 4x ds_write_b128 per thread per K-step, no cvt. Grid 1024 blocks (4/CU).
// TRANS==0: out[b,h,s,hd]  (q, k)
// TRANS==1: out[b,h,hd,s]  (vT) — MFMA operands swapped so the accumulator
//           is transposed and the epilogue writes contiguous s-runs.
// ---------------------------------------------------------------------------
template <int TRANS>
__global__ __launch_bounds__(256) void gemm_proj(
    const __hip_bfloat16* __restrict__ X, const __hip_bfloat16* __restrict__ W,
    const float* __restrict__ bias, __hip_bfloat16* __restrict__ out) {
  // stride 72 elems = 144 B: 16B-aligned ds_read_b128, worst 2-way banks (free)
  __shared__ __hip_bfloat16 As[64][72];
  __shared__ __hip_bfloat16 Bs[64][72];
  const int tid = threadIdx.x;
  const int lane = tid & 63;
  const int wave = tid >> 6;
  const int wr = wave >> 1, wc = wave & 1;   // wave grid 2x2 over 64x64
  const int l15 = lane & 15, quad = lane >> 4;
  const int h = blockIdx.x;                  // one head per 64-wide n-tile
  const int n0 = h * 64;
  const int m0 = blockIdx.y * 64;

  f32x4 acc[2][2] = {};

  for (int k0 = 0; k0 < D; k0 += 64) {
#pragma unroll
    for (int i = 0; i < 2; ++i) {
      int idx = tid + i * 256;
      int r = idx >> 3, c8 = idx & 7;
      *(bf16x8*)&As[r][c8 * 8] = *(const bf16x8*)&X[(size_t)(m0 + r) * D + k0 + c8 * 8];
      *(bf16x8*)&Bs[r][c8 * 8] = *(const bf16x8*)&W[(size_t)(n0 + r) * D + k0 + c8 * 8];
    }
    __syncthreads();

    bf16x8 a[2][2], b[2][2];
#pragma unroll
    for (int mf = 0; mf < 2; ++mf) {
      a[mf][0] = *(const bf16x8*)&As[wr * 32 + mf * 16 + l15][quad * 8];
      a[mf][1] = *(const bf16x8*)&As[wr * 32 + mf * 16 + l15][32 + quad * 8];
    }
#pragma unroll
    for (int nf = 0; nf < 2; ++nf) {
      b[nf][0] = *(const bf16x8*)&Bs[wc * 32 + nf * 16 + l15][quad * 8];
      b[nf][1] = *(const bf16x8*)&Bs[wc * 32 + nf * 16 + l15][32 + quad * 8];
    }
#pragma unroll
    for (int mf = 0; mf < 2; ++mf)
#pragma unroll
      for (int nf = 0; nf < 2; ++nf) {
        if (TRANS) {
          acc[mf][nf] = __builtin_amdgcn_mfma_f32_16x16x32_bf16(b[nf][0], a[mf][0], acc[mf][nf], 0, 0, 0);
          acc[mf][nf] = __builtin_amdgcn_mfma_f32_16x16x32_bf16(b[nf][1], a[mf][1], acc[mf][nf], 0, 0, 0);
        } else {
          acc[mf][nf] = __builtin_amdgcn_mfma_f32_16x16x32_bf16(a[mf][0], b[nf][0], acc[mf][nf], 0, 0, 0);
          acc[mf][nf] = __builtin_amdgcn_mfma_f32_16x16x32_bf16(a[mf][1], b[nf][1], acc[mf][nf], 0, 0, 0);
        }
      }
    __syncthreads();
  }

  if (!TRANS) {
#pragma unroll
    for (int mf = 0; mf < 2; ++mf)
#pragma unroll
      for (int r = 0; r < 4; ++r) {
        int m = m0 + wr * 32 + mf * 16 + quad * 4 + r;
        int bb = m >> 11, s = m & 2047;
        __hip_bfloat16* obh = out + (size_t)bb * STRIDE_B + (size_t)h * STRIDE_BH;
#pragma unroll
        for (int nf = 0; nf < 2; ++nf) {
          int hd = wc * 32 + nf * 16 + l15;
          obh[(size_t)s * HD + hd] =
              __float2bfloat16(acc[mf][nf][r] + bias[n0 + hd]);
        }
      }
  } else {
    // swapped operands -> row = n (hd), col = m (s): contiguous-s writes
#pragma unroll
    for (int mf = 0; mf < 2; ++mf)
#pragma unroll
      for (int r = 0; r < 4; ++r)
#pragma unroll
        for (int nf = 0; nf < 2; ++nf) {
          int hd = wc * 32 + nf * 16 + quad * 4 + r;
          int m = m0 + wr * 32 + mf * 16 + l15;
          int bb = m >> 11, s = m & 2047;
          __hip_bfloat16* obh = out + (size_t)bb * STRIDE_B + (size_t)h * STRIDE_BH;
          obh[(size_t)hd * S + s] =
              __float2bfloat16(acc[mf][nf][r] + bias[n0 + hd]);
        }
  }
}

// ---------------------------------------------------------------------------
// Fused attention. Two passes over key-tiles; mask is the packed bitmask
// (4 broadcast u64 loads per wave per k-tile, L2-resident). dist stores are
// nontemporal so the 268 MB stream doesn't thrash L2 for K/V/mask.
// O written bf16 directly into flat [B,S,D].
// ---------------------------------------------------------------------------
__global__ __launch_bounds__(256) void attn_fused(
    const __hip_bfloat16* __restrict__ q, const __hip_bfloat16* __restrict__ k,
    const __hip_bfloat16* __restrict__ vT,
    const unsigned long long* __restrict__ mbits,
    float* __restrict__ dist, __hip_bfloat16* __restrict__ attn) {
  __shared__ __hip_bfloat16 ps[4][16][72];   // per-wave P strip

  const int tid = threadIdx.x;
  const int wave = tid >> 6;
  const int lane = tid & 63;
  const int l15 = lane & 15;
  const int quad = lane >> 4;
  const int qt = blockIdx.x >> 5;            // consecutive blocks share the mask
  const int bh = blockIdx.x & 31;            // strip (8 heads per batch) -> L2 reuse
  const int b = bh >> 3;
  const int row0 = qt * 64 + wave * 16;      // this wave's 16 query rows

  const __hip_bfloat16* qb  = q  + (size_t)bh * STRIDE_BH;
  const __hip_bfloat16* kb  = k  + (size_t)bh * STRIDE_BH;
  const __hip_bfloat16* vtb = vT + (size_t)bh * STRIDE_BH;   // [HD][S]
  const unsigned long long* mb64 = mbits + (size_t)b * S * SW64;
  float* distb = dist + (size_t)bh * S * S;
  __hip_bfloat16* af = attn + (size_t)b * S * D + (size_t)(bh & 7) * HD;

  const bf16x8 qf0 = *(const bf16x8*)(qb + (size_t)(row0 + l15) * HD + quad * 8);
  const bf16x8 qf1 = *(const bf16x8*)(qb + (size_t)(row0 + l15) * HD + 32 + quad * 8);

  float lpart[4] = {0.f, 0.f, 0.f, 0.f};

  // ---- pass A: row sums ----
  for (int kt = 0; kt < 32; ++kt) {
    const int col0 = kt * 64;
    unsigned long long mw[4];
#pragma unroll
    for (int r = 0; r < 4; ++r)
      mw[r] = mb64[(size_t)(row0 + quad * 4 + r) * SW64 + kt];
#pragma unroll
    for (int ct = 0; ct < 4; ++ct) {
      const int col = col0 + ct * 16 + l15;
      const bf16x8 kf0 = *(const bf16x8*)(kb + (size_t)col * HD + quad * 8);
      const bf16x8 kf1 = *(const bf16x8*)(kb + (size_t)col * HD + 32 + quad * 8);
      f32x4 s = {0.f, 0.f, 0.f, 0.f};
      s = __builtin_amdgcn_mfma_f32_16x16x32_bf16(qf0, kf0, s, 0, 0, 0);
      s = __builtin_amdgcn_mfma_f32_16x16x32_bf16(qf1, kf1, s, 0, 0, 0);
#pragma unroll
      for (int r = 0; r < 4; ++r) {
        int msk = (int)((mw[r] >> (ct * 16 + l15)) & 1ull);
        float e = msk ? 0.f : __expf(s[r] * 0.125f);
        lpart[r] += e;
      }
    }
  }
#pragma unroll
  for (int r = 0; r < 4; ++r) {
    float v = lpart[r];
    v += __shfl_xor(v, 1, 64);
    v += __shfl_xor(v, 2, 64);
    v += __shfl_xor(v, 4, 64);
    v += __shfl_xor(v, 8, 64);
    lpart[r] = 1.0f / v;
  }

  // ---- pass B: dist write + O = P.V ----
  f32x4 oacc[4] = {{0.f, 0.f, 0.f, 0.f}, {0.f, 0.f, 0.f, 0.f},
                   {0.f, 0.f, 0.f, 0.f}, {0.f, 0.f, 0.f, 0.f}};
  for (int kt = 0; kt < 32; ++kt) {
    const int col0 = kt * 64;
    unsigned long long mw[4];
#pragma unroll
    for (int r = 0; r < 4; ++r)
      mw[r] = mb64[(size_t)(row0 + quad * 4 + r) * SW64 + kt];
#pragma unroll
    for (int ct = 0; ct < 4; ++ct) {
      const int col = col0 + ct * 16 + l15;
      const bf16x8 kf0 = *(const bf16x8*)(kb + (size_t)col * HD + quad * 8);
      const bf16x8 kf1 = *(const bf16x8*)(kb + (size_t)col * HD + 32 + quad * 8);
      f32x4 s = {0.f, 0.f, 0.f, 0.f};
      s = __builtin_amdgcn_mfma_f32_16x16x32_bf16(qf0, kf0, s, 0, 0, 0);
      s = __builtin_amdgcn_mfma_f32_16x16x32_bf16(qf1, kf1, s, 0, 0, 0);
#pragma unroll
      for (int r = 0; r < 4; ++r) {
        int row = row0 + quad * 4 + r;
        int msk = (int)((mw[r] >> (ct * 16 + l15)) & 1ull);
        float e = msk ? 0.f : __expf(s[r] * 0.125f);
        float p = e * lpart[r];
        __builtin_nontemporal_store(p, &distb[(size_t)row * S + col]);
        ps[wave][quad * 4 + r][ct * 16 + l15] = __float2bfloat16(p);
      }
    }
    // P strip is wave-private: lgkmcnt tracking covers the same-wave LDS RAW.
    const bf16x8 pa0 = *(const bf16x8*)&ps[wave][l15][quad * 8];
    const bf16x8 pa1 = *(const bf16x8*)&ps[wave][l15][32 + quad * 8];
#pragma unroll
    for (int ct = 0; ct < 4; ++ct) {
      const __hip_bfloat16* vrow = vtb + (size_t)(ct * 16 + l15) * S + col0;
      const bf16x8 vf0 = *(const bf16x8*)(vrow + quad * 8);
      const bf16x8 vf1 = *(const bf16x8*)(vrow + 32 + quad * 8);
      oacc[ct] = __builtin_amdgcn_mfma_f32_16x16x32_bf16(pa0, vf0, oacc[ct], 0, 0, 0);
      oacc[ct] = __builtin_amdgcn_mfma_f32_16x16x32_bf16(pa1, vf1, oacc[ct], 0, 0, 0);
    }
  }

  // write O as bf16 into flat [B,S,D]
#pragma unroll
  for (int ct = 0; ct < 4; ++ct)
#pragma unroll
    for (int r = 0; r < 4; ++r) {
      int row = row0 + quad * 4 + r;
      af[(size_t)row * D + ct * 16 + l15] = __float2bfloat16(oacc[ct][r]);
    }
}

// ---------------------------------------------------------------------------
// Output GEMM (pure bf16 MFMA): x[m,n] = sum_k attn_flat[m,k]*Wo[n,k] + bo[n].
// 64x64 tile, fp32 accumulate + fp32 output.
// ---------------------------------------------------------------------------
__global__ __launch_bounds__(256) void gemm_out(
    const __hip_bfloat16* __restrict__ Abf, const __hip_bfloat16* __restrict__ W,
    const float* __restrict__ bias, float* __restrict__ outp) {
  __shared__ __hip_bfloat16 As[64][72];
  __shared__ __hip_bfloat16 Bs[64][72];
  const int tid = threadIdx.x;
  const int lane = tid & 63;
  const int wave = tid >> 6;
  const int wr = wave >> 1, wc = wave & 1;
  const int l15 = lane & 15, quad = lane >> 4;
  const int n0 = blockIdx.x * 64;
  const int m0 = blockIdx.y * 64;

  f32x4 acc[2][2] = {};

  for (int k0 = 0; k0 < D; k0 += 64) {
#pragma unroll
    for (int i = 0; i < 2; ++i) {
      int idx = tid + i * 256;
      int r = idx >> 3, c8 = idx & 7;
      *(bf16x8*)&As[r][c8 * 8] = *(const bf16x8*)&Abf[(size_t)(m0 + r) * D + k0 + c8 * 8];
      *(bf16x8*)&Bs[r][c8 * 8] = *(const bf16x8*)&W[(size_t)(n0 + r) * D + k0 + c8 * 8];
    }
    __syncthreads();

    bf16x8 a[2][2], b[2][2];
#pragma unroll
    for (int mf = 0; mf < 2; ++mf) {
      a[mf][0] = *(const bf16x8*)&As[wr * 32 + mf * 16 + l15][quad * 8];
      a[mf][1] = *(const bf16x8*)&As[wr * 32 + mf * 16 + l15][32 + quad * 8];
    }
#pragma unroll
    for (int nf = 0; nf < 2; ++nf) {
      b[nf][0] = *(const bf16x8*)&Bs[wc * 32 + nf * 16 + l15][quad * 8];
      b[nf][1] = *(const bf16x8*)&Bs[wc * 32 + nf * 16 + l15][32 + quad * 8];
    }
#pragma unroll
    for (int mf = 0; mf < 2; ++mf)
#pragma unroll
      for (int nf = 0; nf < 2; ++nf) {
        acc[mf][nf] = __builtin_amdgcn_mfma_f32_16x16x32_bf16(a[mf][0], b[nf][0], acc[mf][nf], 0, 0, 0);
        acc[mf][nf] = __builtin_amdgcn_mfma_f32_16x16x32_bf16(a[mf][1], b[nf][1], acc[mf][nf], 0, 0, 0);
      }
    __syncthreads();
  }

#pragma unroll
  for (int mf = 0; mf < 2; ++mf)
#pragma unroll
    for (int r = 0; r < 4; ++r) {
      int m = m0 + wr * 32 + mf * 16 + quad * 4 + r;
#pragma unroll
      for (int nf = 0; nf < 2; ++nf) {
        int n = n0 + wc * 32 + nf * 16 + l15;
        outp[(size_t)m * D + n] = acc[mf][nf][r] + bias[n];
      }
    }
}

// ---------------------------------------------------------------------------
extern "C" void kernel_launch(void* const* d_in, const int* in_sizes, int n_in,
                              void* d_out, int out_size, void* d_ws, size_t ws_size,
                              hipStream_t stream) {
  const float* Q    = (const float*)d_in[0];
  const float* K    = (const float*)d_in[1];
  const float* V    = (const float*)d_in[2];
  const int*   mask = (const int*)d_in[3];
  const float* Wq   = (const float*)d_in[4];
  const float* bq   = (const float*)d_in[5];
  const float* Wk   = (const float*)d_in[6];
  const float* bk   = (const float*)d_in[7];
  const float* Wv   = (const float*)d_in[8];
  const float* bv   = (const float*)d_in[9];
  const float* Wo   = (const float*)d_in[10];
  const float* bo   = (const float*)d_in[11];

  float* x_out = (float*)d_out;              // [B,S,D]
  float* dist  = x_out + (size_t)X_SIZE;     // [B,H,S,S]

  // Workspace layout (bf16 unless noted):
  //  Qb | Kb | Vb (X_SIZE each) | Wqb Wkb Wvb Wob (D*D each)
  //  | qb | kbf | vtb (X_SIZE each) | mbits (u64, B*S*SW64)
  //  abf (flat O, X_SIZE) aliases Qb -- Qb is dead after the q-projection.
  __hip_bfloat16* cvtb = (__hip_bfloat16*)d_ws;
  __hip_bfloat16* Qb   = cvtb;
  __hip_bfloat16* Kb   = Qb + (size_t)X_SIZE;
  __hip_bfloat16* Vb   = Kb + (size_t)X_SIZE;
  __hip_bfloat16* Wqb  = Vb + (size_t)X_SIZE;
  __hip_bfloat16* Wkb  = Wqb + (size_t)D * D;
  __hip_bfloat16* Wvb  = Wkb + (size_t)D * D;
  __hip_bfloat16* Wob  = Wvb + (size_t)D * D;
  __hip_bfloat16* qb   = Wob + (size_t)D * D;
  __hip_bfloat16* kbf  = qb + (size_t)X_SIZE;
  __hip_bfloat16* vtb  = kbf + (size_t)X_SIZE;
  unsigned long long* mbits = (unsigned long long*)(vtb + (size_t)X_SIZE);
  __hip_bfloat16* abf  = Qb;                 // alias (see above)

  dim3 blk(256);
  dim3 g(D / 64, M_TOT / 64);                // (8, 128) = 1024 blocks

  cvt_all<<<dim3(2048), blk, 0, stream>>>(Q, K, V, Wq, Wk, Wv, Wo, cvtb);
  mask_pack<<<dim3(1024), blk, 0, stream>>>(mask, mbits);
  gemm_proj<0><<<g, blk, 0, stream>>>(Qb, Wqb, bq, qb);
  gemm_proj<0><<<g, blk, 0, stream>>>(Kb, Wkb, bk, kbf);
  gemm_proj<1><<<g, blk, 0, stream>>>(Vb, Wvb, bv, vtb);
  attn_fused<<<dim3(B * H * S / 64), blk, 0, stream>>>(qb, kbf, vtb, mbits, dist, abf);
  gemm_out<<<g, blk, 0, stream>>>(abf, Wob, bo, x_out);
}

// Round 3
// 889.891 us; speedup vs baseline: 1.6795x; 1.1435x over previous
//
#include <hip/hip_runtime.h>
#include <hip/hip_bf16.h>
#include <math.h>

// Problem constants
#define B 4
#define S 2048
#define D 512
#define H 8
#define HD 64
#define M_TOT (B * S)              // 8192 rows in the [B*S, D] view
#define X_SIZE (B * S * D)         // 4194304 elements
#define STRIDE_BH (S * HD)         // 131072  ([B,H,S,HD] h-stride)
#define STRIDE_B (H * S * HD)      // 1048576 ([B,H,S,HD] b-stride)
#define SW64 (S / 64)              // 32 mask words per row

typedef __attribute__((ext_vector_type(8))) short bf16x8;
typedef __attribute__((ext_vector_type(4))) float f32x4;

// 16B async global->LDS. LDS dest is wave-uniform base + lane*16 (HW).
__device__ __forceinline__ void gld_lds16(const void* g, void* l) {
  __builtin_amdgcn_global_load_lds(
      (const __attribute__((address_space(1))) unsigned int*)g,
      (__attribute__((address_space(3))) unsigned int*)l, 16, 0, 0);
}

// ---------------------------------------------------------------------------
// cvt_all: one pass converting Q,K,V (fp32 [B*S,D]) and Wq,Wk,Wv,Wo (fp32
// [D,D]) to bf16, laid out contiguously: Qb | Kb | Vb | Wqb | Wkb | Wvb | Wob
// ---------------------------------------------------------------------------
__global__ __launch_bounds__(256) void cvt_all(
    const float* __restrict__ Q, const float* __restrict__ K,
    const float* __restrict__ V, const float* __restrict__ Wq,
    const float* __restrict__ Wk, const float* __restrict__ Wv,
    const float* __restrict__ Wo, __hip_bfloat16* __restrict__ outb) {
  const int NX = X_SIZE / 8;           // 524288 chunks of 8 floats
  const int NW = (D * D) / 8;          // 32768
  const int total = 3 * NX + 4 * NW;
  int c = blockIdx.x * 256 + threadIdx.x;
  const int stride = gridDim.x * 256;
  for (; c < total; c += stride) {
    const float* src;
    int off;
    if (c < NX)          { src = Q;  off = c; }
    else if (c < 2 * NX) { src = K;  off = c - NX; }
    else if (c < 3 * NX) { src = V;  off = c - 2 * NX; }
    else {
      int wc = c - 3 * NX;
      int wi = wc >> 15;
      src = (wi == 0) ? Wq : (wi == 1) ? Wk : (wi == 2) ? Wv : Wo;
      off = wc & (NW - 1);
    }
    const float4 x0 = *(const float4*)&src[(size_t)off * 8];
    const float4 x1 = *(const float4*)&src[(size_t)off * 8 + 4];
    bf16x8 pk;
    __hip_bfloat16* p = (__hip_bfloat16*)&pk;
    p[0] = __float2bfloat16(x0.x); p[1] = __float2bfloat16(x0.y);
    p[2] = __float2bfloat16(x0.z); p[3] = __float2bfloat16(x0.w);
    p[4] = __float2bfloat16(x1.x); p[5] = __float2bfloat16(x1.y);
    p[6] = __float2bfloat16(x1.z); p[7] = __float2bfloat16(x1.w);
    *(bf16x8*)&outb[(size_t)c * 8] = pk;
  }
}

// ---------------------------------------------------------------------------
// mask_pack: [B,S,S] int32 -> [B,S,S/64] u64 bitmask via wave ballot.
// ---------------------------------------------------------------------------
__global__ __launch_bounds__(256) void mask_pack(
    const int* __restrict__ mask, unsigned long long* __restrict__ mbits) {
  const int lane = threadIdx.x & 63;
  const int wid = threadIdx.x >> 6;
  const size_t nwords = (size_t)B * S * SW64;
  size_t w = (size_t)blockIdx.x * 4 + wid;
  const size_t stride = (size_t)gridDim.x * 4;
  for (; w < nwords; w += stride) {
    int m = mask[w * 64 + lane];
    unsigned long long bits = __ballot(m != 0);
    if (lane == 0) mbits[w] = bits;
  }
}

// ---------------------------------------------------------------------------
// Fused Q/K/V projection GEMM (bf16 MFMA): one launch, blockIdx.z selects
// which projection. 64x64 tile, BK=64, 4 waves, T14 register prefetch
// (issue next k-step's loads right after the barrier, before the MFMAs).
// z==2 (V): MFMA operands swapped -> transposed acc -> contiguous-s writes
// into the [b,h,hd,s] vT layout.
// ---------------------------------------------------------------------------
__global__ __launch_bounds__(256) void gemm_qkv(
    const __hip_bfloat16* __restrict__ Xall, const __hip_bfloat16* __restrict__ Wall,
    const float* __restrict__ bq, const float* __restrict__ bk,
    const float* __restrict__ bv, __hip_bfloat16* __restrict__ outall) {
  __shared__ __hip_bfloat16 As[64][72];   // stride 144B: 2-way banks (free)
  __shared__ __hip_bfloat16 Bs[64][72];
  const int z = blockIdx.z;
  const __hip_bfloat16* X = Xall + (size_t)z * X_SIZE;
  const __hip_bfloat16* W = Wall + (size_t)z * (D * D);
  const float* bias = (z == 0) ? bq : (z == 1) ? bk : bv;
  __hip_bfloat16* out = outall + (size_t)z * X_SIZE;
  const bool trans = (z == 2);

  const int tid = threadIdx.x;
  const int lane = tid & 63;
  const int wave = tid >> 6;
  const int wr = wave >> 1, wc = wave & 1;
  const int l15 = lane & 15, quad = lane >> 4;
  const int h = blockIdx.x;
  const int n0 = h * 64;
  const int m0 = blockIdx.y * 64;
  const int r_ = tid >> 3, c8 = tid & 7;  // staging coords (i adds 32 rows)

  bf16x8 xr[2], wv[2];
#pragma unroll
  for (int i = 0; i < 2; ++i) {
    xr[i] = *(const bf16x8*)&X[(size_t)(m0 + r_ + i * 32) * D + c8 * 8];
    wv[i] = *(const bf16x8*)&W[(size_t)(n0 + r_ + i * 32) * D + c8 * 8];
  }
  f32x4 acc[2][2] = {};

  for (int k0 = 0; k0 < D; k0 += 64) {
#pragma unroll
    for (int i = 0; i < 2; ++i) {
      *(bf16x8*)&As[r_ + i * 32][c8 * 8] = xr[i];
      *(bf16x8*)&Bs[r_ + i * 32][c8 * 8] = wv[i];
    }
    __syncthreads();
    if (k0 + 64 < D) {                       // prefetch next step (overlaps MFMAs)
#pragma unroll
      for (int i = 0; i < 2; ++i) {
        xr[i] = *(const bf16x8*)&X[(size_t)(m0 + r_ + i * 32) * D + (k0 + 64) + c8 * 8];
        wv[i] = *(const bf16x8*)&W[(size_t)(n0 + r_ + i * 32) * D + (k0 + 64) + c8 * 8];
      }
    }
    bf16x8 a[2][2], b[2][2];
#pragma unroll
    for (int mf = 0; mf < 2; ++mf) {
      a[mf][0] = *(const bf16x8*)&As[wr * 32 + mf * 16 + l15][quad * 8];
      a[mf][1] = *(const bf16x8*)&As[wr * 32 + mf * 16 + l15][32 + quad * 8];
    }
#pragma unroll
    for (int nf = 0; nf < 2; ++nf) {
      b[nf][0] = *(const bf16x8*)&Bs[wc * 32 + nf * 16 + l15][quad * 8];
      b[nf][1] = *(const bf16x8*)&Bs[wc * 32 + nf * 16 + l15][32 + quad * 8];
    }
    if (trans) {
#pragma unroll
      for (int mf = 0; mf < 2; ++mf)
#pragma unroll
        for (int nf = 0; nf < 2; ++nf) {
          acc[mf][nf] = __builtin_amdgcn_mfma_f32_16x16x32_bf16(b[nf][0], a[mf][0], acc[mf][nf], 0, 0, 0);
          acc[mf][nf] = __builtin_amdgcn_mfma_f32_16x16x32_bf16(b[nf][1], a[mf][1], acc[mf][nf], 0, 0, 0);
        }
    } else {
#pragma unroll
      for (int mf = 0; mf < 2; ++mf)
#pragma unroll
        for (int nf = 0; nf < 2; ++nf) {
          acc[mf][nf] = __builtin_amdgcn_mfma_f32_16x16x32_bf16(a[mf][0], b[nf][0], acc[mf][nf], 0, 0, 0);
          acc[mf][nf] = __builtin_amdgcn_mfma_f32_16x16x32_bf16(a[mf][1], b[nf][1], acc[mf][nf], 0, 0, 0);
        }
    }
    __syncthreads();
  }

  if (!trans) {
#pragma unroll
    for (int mf = 0; mf < 2; ++mf)
#pragma unroll
      for (int r = 0; r < 4; ++r) {
        int m = m0 + wr * 32 + mf * 16 + quad * 4 + r;
        int bb = m >> 11, s = m & 2047;
        __hip_bfloat16* obh = out + (size_t)bb * STRIDE_B + (size_t)h * STRIDE_BH;
#pragma unroll
        for (int nf = 0; nf < 2; ++nf) {
          int hd = wc * 32 + nf * 16 + l15;
          obh[(size_t)s * HD + hd] = __float2bfloat16(acc[mf][nf][r] + bias[n0 + hd]);
        }
      }
  } else {
#pragma unroll
    for (int mf = 0; mf < 2; ++mf)
#pragma unroll
      for (int r = 0; r < 4; ++r)
#pragma unroll
        for (int nf = 0; nf < 2; ++nf) {
          int hd = wc * 32 + nf * 16 + quad * 4 + r;
          int m = m0 + wr * 32 + mf * 16 + l15;
          int bb = m >> 11, s = m & 2047;
          __hip_bfloat16* obh = out + (size_t)bb * STRIDE_B + (size_t)h * STRIDE_BH;
          obh[(size_t)hd * S + s] = __float2bfloat16(acc[mf][nf][r] + bias[n0 + hd]);
        }
  }
}

// ---------------------------------------------------------------------------
// Fused attention v3. Block-cooperative K/V staging into LDS via
// global_load_lds (16B, pre-swizzled global source -> linear LDS dest lands
// XOR-swizzled), double-buffered, stage issued at top of each iter so HBM/L3
// latency hides under MFMA+VALU. All tiles use the same swizzle: LDS chunk c
// of row r holds source 16B-chunk (c ^ (r&7)); reads XOR the same way ->
// conflict-free ds_read_b128. Two passes (rowsum, then dist+PV) as before.
// ---------------------------------------------------------------------------
__global__ __launch_bounds__(256) void attn_fused(
    const __hip_bfloat16* __restrict__ q, const __hip_bfloat16* __restrict__ k,
    const __hip_bfloat16* __restrict__ vT,
    const unsigned long long* __restrict__ mbits,
    float* __restrict__ dist, __hip_bfloat16* __restrict__ attn) {
  __shared__ __hip_bfloat16 Kt[2][64][64];   // 16 KB
  __shared__ __hip_bfloat16 Vt[2][64][64];   // 16 KB
  __shared__ __hip_bfloat16 ps[4][16][64];   // 8 KB (swizzled, no pad)

  const int tid = threadIdx.x;
  const int wave = tid >> 6;
  const int lane = tid & 63;
  const int l15 = lane & 15;
  const int quad = lane >> 4;
  const int sw = l15 & 7;
  const int c0q = (quad ^ sw) << 3;          // elem offset of swizzled chunk quad
  const int c1q = ((4 | quad) ^ sw) << 3;    // .. chunk 4+quad
  const int qt = blockIdx.x >> 5;
  const int bh = blockIdx.x & 31;
  const int b = bh >> 3;
  const int row0 = qt * 64 + wave * 16;

  const __hip_bfloat16* qb  = q  + (size_t)bh * STRIDE_BH;
  const __hip_bfloat16* kb  = k  + (size_t)bh * STRIDE_BH;
  const __hip_bfloat16* vtb = vT + (size_t)bh * STRIDE_BH;   // [HD][S]
  const unsigned long long* mb64 = mbits + (size_t)b * S * SW64;
  float* distb = dist + (size_t)bh * S * S;
  __hip_bfloat16* af = attn + (size_t)b * S * D + (size_t)(bh & 7) * HD;

  // staging lane geometry: 8 rows x 128B per gld_lds16; source chunk
  // pre-swizzled so linear LDS dest = swizzled layout.
  const int sr = lane >> 3;
  const int schunk = ((lane & 7) ^ sr) * 16;  // bytes

  const bf16x8 qf0 = *(const bf16x8*)(qb + (size_t)(row0 + l15) * HD + quad * 8);
  const bf16x8 qf1 = *(const bf16x8*)(qb + (size_t)(row0 + l15) * HD + 32 + quad * 8);

  auto stageK = [&](int buf, int kt) {
    const char* g0 = (const char*)(kb + (size_t)(kt * 64 + wave * 16) * HD);
#pragma unroll
    for (int hh = 0; hh < 2; ++hh)
      gld_lds16(g0 + (size_t)(hh * 8 + sr) * 128 + schunk,
                &Kt[buf][wave * 16 + hh * 8][0]);
  };
  auto stageV = [&](int buf, int kt) {
    const char* g0 = (const char*)(vtb + (size_t)(wave * 16) * S + kt * 64);
#pragma unroll
    for (int hh = 0; hh < 2; ++hh)
      gld_lds16(g0 + (size_t)(hh * 8 + sr) * (S * 2) + schunk,
                &Vt[buf][wave * 16 + hh * 8][0]);
  };

  float lpart[4] = {0.f, 0.f, 0.f, 0.f};

  // ---- pass A: row sums ----
  stageK(0, 0);
  __syncthreads();
  for (int kt = 0; kt < 32; ++kt) {
    const int buf = kt & 1;
    if (kt < 31) stageK(buf ^ 1, kt + 1);
    unsigned long long mw[4];
#pragma unroll
    for (int r = 0; r < 4; ++r)
      mw[r] = mb64[(size_t)(row0 + quad * 4 + r) * SW64 + kt];
#pragma unroll
    for (int ct = 0; ct < 4; ++ct) {
      const __hip_bfloat16* Krow = &Kt[buf][ct * 16 + l15][0];
      const bf16x8 kf0 = *(const bf16x8*)(Krow + c0q);
      const bf16x8 kf1 = *(const bf16x8*)(Krow + c1q);
      f32x4 s = {0.f, 0.f, 0.f, 0.f};
      s = __builtin_amdgcn_mfma_f32_16x16x32_bf16(qf0, kf0, s, 0, 0, 0);
      s = __builtin_amdgcn_mfma_f32_16x16x32_bf16(qf1, kf1, s, 0, 0, 0);
#pragma unroll
      for (int r = 0; r < 4; ++r) {
        int msk = (int)((mw[r] >> (ct * 16 + l15)) & 1ull);
        float e = msk ? 0.f : __expf(s[r] * 0.125f);
        lpart[r] += e;
      }
    }
    __syncthreads();
  }
#pragma unroll
  for (int r = 0; r < 4; ++r) {
    float v = lpart[r];
    v += __shfl_xor(v, 1, 64);
    v += __shfl_xor(v, 2, 64);
    v += __shfl_xor(v, 4, 64);
    v += __shfl_xor(v, 8, 64);
    lpart[r] = 1.0f / v;
  }

  // ---- pass B: dist write + O = P.V ----
  f32x4 oacc[4] = {{0.f, 0.f, 0.f, 0.f}, {0.f, 0.f, 0.f, 0.f},
                   {0.f, 0.f, 0.f, 0.f}, {0.f, 0.f, 0.f, 0.f}};
  stageK(0, 0);
  stageV(0, 0);
  __syncthreads();
  for (int kt = 0; kt < 32; ++kt) {
    const int buf = kt & 1;
    if (kt < 31) { stageK(buf ^ 1, kt + 1); stageV(buf ^ 1, kt + 1); }
    const int col0 = kt * 64;
    unsigned long long mw[4];
#pragma unroll
    for (int r = 0; r < 4; ++r)
      mw[r] = mb64[(size_t)(row0 + quad * 4 + r) * SW64 + kt];
#pragma unroll
    for (int ct = 0; ct < 4; ++ct) {
      const __hip_bfloat16* Krow = &Kt[buf][ct * 16 + l15][0];
      const bf16x8 kf0 = *(const bf16x8*)(Krow + c0q);
      const bf16x8 kf1 = *(const bf16x8*)(Krow + c1q);
      f32x4 s = {0.f, 0.f, 0.f, 0.f};
      s = __builtin_amdgcn_mfma_f32_16x16x32_bf16(qf0, kf0, s, 0, 0, 0);
      s = __builtin_amdgcn_mfma_f32_16x16x32_bf16(qf1, kf1, s, 0, 0, 0);
#pragma unroll
      for (int r = 0; r < 4; ++r) {
        int row = row0 + quad * 4 + r;
        int msk = (int)((mw[r] >> (ct * 16 + l15)) & 1ull);
        float e = msk ? 0.f : __expf(s[r] * 0.125f);
        float p = e * lpart[r];
        __builtin_nontemporal_store(p, &distb[(size_t)row * S + col0 + ct * 16 + l15]);
        int prow = quad * 4 + r;
        int chunk = (ct * 2 + (l15 >> 3)) ^ (prow & 7);
        ps[wave][prow][chunk * 8 + (l15 & 7)] = __float2bfloat16(p);
      }
    }
    // ps is wave-private: same-wave lgkmcnt tracking covers the RAW.
    const bf16x8 pa0 = *(const bf16x8*)&ps[wave][l15][c0q];
    const bf16x8 pa1 = *(const bf16x8*)&ps[wave][l15][c1q];
#pragma unroll
    for (int ct = 0; ct < 4; ++ct) {
      const __hip_bfloat16* Vrow = &Vt[buf][ct * 16 + l15][0];
      const bf16x8 vf0 = *(const bf16x8*)(Vrow + c0q);
      const bf16x8 vf1 = *(const bf16x8*)(Vrow + c1q);
      oacc[ct] = __builtin_amdgcn_mfma_f32_16x16x32_bf16(pa0, vf0, oacc[ct], 0, 0, 0);
      oacc[ct] = __builtin_amdgcn_mfma_f32_16x16x32_bf16(pa1, vf1, oacc[ct], 0, 0, 0);
    }
    __syncthreads();
  }

  // write O as bf16 into flat [B,S,D]
#pragma unroll
  for (int ct = 0; ct < 4; ++ct)
#pragma unroll
    for (int r = 0; r < 4; ++r) {
      int row = row0 + quad * 4 + r;
      af[(size_t)row * D + ct * 16 + l15] = __float2bfloat16(oacc[ct][r]);
    }
}

// ---------------------------------------------------------------------------
// Output GEMM (bf16 MFMA + T14 prefetch): x = attn_flat @ Wo^T + bo, fp32 out.
// ---------------------------------------------------------------------------
__global__ __launch_bounds__(256) void gemm_out(
    const __hip_bfloat16* __restrict__ Abf, const __hip_bfloat16* __restrict__ W,
    const float* __restrict__ bias, float* __restrict__ outp) {
  __shared__ __hip_bfloat16 As[64][72];
  __shared__ __hip_bfloat16 Bs[64][72];
  const int tid = threadIdx.x;
  const int lane = tid & 63;
  const int wave = tid >> 6;
  const int wr = wave >> 1, wc = wave & 1;
  const int l15 = lane & 15, quad = lane >> 4;
  const int n0 = blockIdx.x * 64;
  const int m0 = blockIdx.y * 64;
  const int r_ = tid >> 3, c8 = tid & 7;

  bf16x8 xr[2], wv[2];
#pragma unroll
  for (int i = 0; i < 2; ++i) {
    xr[i] = *(const bf16x8*)&Abf[(size_t)(m0 + r_ + i * 32) * D + c8 * 8];
    wv[i] = *(const bf16x8*)&W[(size_t)(n0 + r_ + i * 32) * D + c8 * 8];
  }
  f32x4 acc[2][2] = {};

  for (int k0 = 0; k0 < D; k0 += 64) {
#pragma unroll
    for (int i = 0; i < 2; ++i) {
      *(bf16x8*)&As[r_ + i * 32][c8 * 8] = xr[i];
      *(bf16x8*)&Bs[r_ + i * 32][c8 * 8] = wv[i];
    }
    __syncthreads();
    if (k0 + 64 < D) {
#pragma unroll
      for (int i = 0; i < 2; ++i) {
        xr[i] = *(const bf16x8*)&Abf[(size_t)(m0 + r_ + i * 32) * D + (k0 + 64) + c8 * 8];
        wv[i] = *(const bf16x8*)&W[(size_t)(n0 + r_ + i * 32) * D + (k0 + 64) + c8 * 8];
      }
    }
    bf16x8 a[2][2], b[2][2];
#pragma unroll
    for (int mf = 0; mf < 2; ++mf) {
      a[mf][0] = *(const bf16x8*)&As[wr * 32 + mf * 16 + l15][quad * 8];
      a[mf][1] = *(const bf16x8*)&As[wr * 32 + mf * 16 + l15][32 + quad * 8];
    }
#pragma unroll
    for (int nf = 0; nf < 2; ++nf) {
      b[nf][0] = *(const bf16x8*)&Bs[wc * 32 + nf * 16 + l15][quad * 8];
      b[nf][1] = *(const bf16x8*)&Bs[wc * 32 + nf * 16 + l15][32 + quad * 8];
    }
#pragma unroll
    for (int mf = 0; mf < 2; ++mf)
#pragma unroll
      for (int nf = 0; nf < 2; ++nf) {
        acc[mf][nf] = __builtin_amdgcn_mfma_f32_16x16x32_bf16(a[mf][0], b[nf][0], acc[mf][nf], 0, 0, 0);
        acc[mf][nf] = __builtin_amdgcn_mfma_f32_16x16x32_bf16(a[mf][1], b[nf][1], acc[mf][nf], 0, 0, 0);
      }
    __syncthreads();
  }

#pragma unroll
  for (int mf = 0; mf < 2; ++mf)
#pragma unroll
    for (int r = 0; r < 4; ++r) {
      int m = m0 + wr * 32 + mf * 16 + quad * 4 + r;
#pragma unroll
      for (int nf = 0; nf < 2; ++nf) {
        int n = n0 + wc * 32 + nf * 16 + l15;
        outp[(size_t)m * D + n] = acc[mf][nf][r] + bias[n];
      }
    }
}

// ---------------------------------------------------------------------------
extern "C" void kernel_launch(void* const* d_in, const int* in_sizes, int n_in,
                              void* d_out, int out_size, void* d_ws, size_t ws_size,
                              hipStream_t stream) {
  const float* Q    = (const float*)d_in[0];
  const float* K    = (const float*)d_in[1];
  const float* V    = (const float*)d_in[2];
  const int*   mask = (const int*)d_in[3];
  const float* Wq   = (const float*)d_in[4];
  const float* bq   = (const float*)d_in[5];
  const float* Wk   = (const float*)d_in[6];
  const float* bk   = (const float*)d_in[7];
  const float* Wv   = (const float*)d_in[8];
  const float* bv   = (const float*)d_in[9];
  const float* Wo   = (const float*)d_in[10];
  const float* bo   = (const float*)d_in[11];

  float* x_out = (float*)d_out;              // [B,S,D]
  float* dist  = x_out + (size_t)X_SIZE;     // [B,H,S,S]

  // Workspace: Qb|Kb|Vb | Wqb Wkb Wvb Wob | qb kbf vtb | mbits
  // abf (flat O) aliases Qb (dead after the q-projection).
  __hip_bfloat16* cvtb = (__hip_bfloat16*)d_ws;
  __hip_bfloat16* Qb   = cvtb;
  __hip_bfloat16* Wqb  = Qb + (size_t)3 * X_SIZE;
  __hip_bfloat16* Wob  = Wqb + (size_t)3 * D * D;
  __hip_bfloat16* qb   = Wob + (size_t)D * D;
  __hip_bfloat16* kbf  = qb + (size_t)X_SIZE;
  __hip_bfloat16* vtb  = kbf + (size_t)X_SIZE;
  unsigned long long* mbits = (unsigned long long*)(vtb + (size_t)X_SIZE);
  __hip_bfloat16* abf  = Qb;                 // alias (see above)

  dim3 blk(256);

  cvt_all<<<dim3(2048), blk, 0, stream>>>(Q, K, V, Wq, Wk, Wv, Wo, cvtb);
  mask_pack<<<dim3(1024), blk, 0, stream>>>(mask, mbits);
  gemm_qkv<<<dim3(D / 64, M_TOT / 64, 3), blk, 0, stream>>>(Qb, Wqb, bq, bk, bv, qb);
  attn_fused<<<dim3(B * H * S / 64), blk, 0, stream>>>(qb, kbf, vtb, mbits, dist, abf);
  gemm_out<<<dim3(D / 64, M_TOT / 64), blk, 0, stream>>>(abf, Wob, bo, x_out);
}